// Round 4
// baseline (203.181 us; speedup 1.0000x reference)
//
#include <hip/hip_runtime.h>
#include <hip/hip_bf16.h>
#include <stdint.h>

#define IN_C 256
#define OUT_C 256
#define HH 56
#define WW 56
#define NB 32
#define HP 58
#define WP 58

#define BM 224        // pixels per block = 4 full output rows
#define NTILE 448     // 32 images * 14 row-groups (= 8*56, XCD-bijective)
#define XSEG 44       // X tile: 6 rows * 58 cols * 64 ic * 2B = 43.5 KB -> 44 segs of 1 KB
#define XBUF_SHORTS 22528   // 45056 B (incl. pad seg)

typedef __attribute__((ext_vector_type(8))) short short8;
typedef __attribute__((ext_vector_type(4))) float float4_t;

typedef const __attribute__((address_space(1))) unsigned int guint_t;
typedef __attribute__((address_space(3))) unsigned int luint_t;

__device__ __forceinline__ unsigned short f2bf(float f) {
    union { float f; unsigned u; } v; v.f = f;
    unsigned r = v.u + 0x7FFF + ((v.u >> 16) & 1);   // RNE
    return (unsigned short)(r >> 16);
}

__device__ __forceinline__ void gload16(void* lds, const void* g) {
    __builtin_amdgcn_global_load_lds((guint_t*)g, (luint_t*)lds, 16, 0, 0);
}

// ---------------- pre-pass 1: NCHW f32 -> padded NHWC bf16 ----------------
__global__ __launch_bounds__(256) void pad_nhwc(const float* __restrict__ x,
                                                unsigned short* __restrict__ xpad) {
    __shared__ float lds[WW * 257];
    int bid = blockIdx.x;
    int n = bid / HP, h = bid % HP;
    unsigned short* dstRow = xpad + (size_t)(n * HP + h) * WP * IN_C;
    bool hin = (h >= 1 && h <= HH);
    if (hin) {
        const float* src = x + (size_t)n * IN_C * (HH * WW) + (h - 1) * WW;
        for (int e = threadIdx.x; e < IN_C * WW; e += 256) {
            int ic = e / WW, w = e - ic * WW;
            lds[w * 257 + ic] = src[(size_t)ic * (HH * WW) + w];
        }
    }
    __syncthreads();
    for (int e = threadIdx.x; e < WP * (IN_C / 8); e += 256) {
        int wo = e / (IN_C / 8);
        int icc = e - wo * (IN_C / 8);
        short8 v = {0, 0, 0, 0, 0, 0, 0, 0};
        if (hin && wo >= 1 && wo <= WW) {
            const float* p = &lds[(wo - 1) * 257 + icc * 8];
#pragma unroll
            for (int j = 0; j < 8; ++j) v[j] = (short)f2bf(p[j]);
        }
        *(short8*)(dstRow + wo * IN_C + icc * 8) = v;
    }
}

// ---------------- pre-pass 2: OIHW f32 -> [oc][tap][ic] bf16 ----------------
__global__ __launch_bounds__(256) void wconv(const float* __restrict__ w,
                                             unsigned short* __restrict__ wt) {
    int o = blockIdx.x * 256 + threadIdx.x;
    if (o < OUT_C * 2304) {
        int oc = o / 2304;
        int rem = o - oc * 2304;
        int khw = rem / 256;
        int ic = rem - khw * 256;
        wt[o] = f2bf(w[(size_t)oc * 2304 + ic * 9 + khw]);
    }
}

// ---------------- main: X-resident-per-q implicit-GEMM, 1 barrier/kt ----------------
// C[oc][pix] = sum over (q=ic/64 outer, tap inner) W[oc][tap][q] * X[pix+tap][q]
__global__ __launch_bounds__(512, 2) void conv_mfma(const unsigned short* __restrict__ xpad,
                                                    const unsigned short* __restrict__ wt,
                                                    float* __restrict__ out) {
    __shared__ unsigned short Wl[2][16384];       // 2 x 256 oc x 64 k (32 KB each)
    __shared__ unsigned short Xl[2][XBUF_SHORTS]; // 2 x (6*58 rc x 64 ic) (44 KB each)

    const int tid = threadIdx.x;
    const int lane = tid & 63;
    const int wid = tid >> 6;
    const int wm = wid >> 1;       // 0..3 : 64-oc slice
    const int wn = wid & 1;        // 0..1 : 112-pixel half

    const int bid = blockIdx.x;
    const int tile = (bid & 7) * 56 + (bid >> 3);   // bijective XCD swizzle
    const int n = tile / 14;
    const int rg = tile - n * 14;
    const int oh0 = rg * 4;        // padded rows oh0 .. oh0+5
    const int pix0 = rg * 224;

    // ---- W staging: 4 chunks/thread; physical (row, pc) holds logical chunk pc^(row&7) ----
    const unsigned short* gw[4];
    {
        const int prow = tid >> 3, ppc = tid & 7;
#pragma unroll
        for (int t = 0; t < 4; ++t) {
            int row = t * 64 + prow;
            int c = ppc ^ (row & 7);
            gw[t] = wt + (size_t)row * 2304 + c * 8;
        }
    }

    // ---- X staging: seg s (1 KB), lane chunk ci = s*64+lane; rc = ci>>3, pc = ci&7 ----
    // physical (rc, pc) holds logical ic-chunk pc^(col&7). Thread's segs: wid + j*8.
    const unsigned short* xpn = xpad + (size_t)n * HP * WP * IN_C;
    int xsoff[6];
#pragma unroll
    for (int j = 0; j < 6; ++j) {
        int s = wid + j * 8;
        int ci = s * 64 + lane;
        int rc = ci >> 3, pc = ci & 7;
        if (rc > 347) rc = 347;                       // pad chunks: clamp (unused data)
        int row = rc / 58, col = rc - row * 58;
        int sc = pc ^ (col & 7);
        xsoff[j] = ((oh0 + row) * WP + col) * IN_C + sc * 8;
    }

    // ---- fragment addressing ----
    const int rlo = lane & 15;
    const int kq = lane >> 4;
    const int swA = rlo & 7;
    const int baseA = (wm * 64 + rlo) * 64;           // W row stride = 64 shorts
    int rcb[7], owl[7];
#pragma unroll
    for (int xf = 0; xf < 7; ++xf) {
        int pl = wn * 112 + xf * 16 + rlo;            // 0..223
        int ohr = pl / 56, ow = pl - ohr * 56;
        rcb[xf] = (ohr * 58 + ow) * 64;               // rc * 64 shorts
        owl[xf] = ow & 7;
    }

    float4_t acc[4][7];
#pragma unroll
    for (int af = 0; af < 4; ++af)
#pragma unroll
        for (int xf = 0; xf < 7; ++xf) acc[af][xf] = {0.f, 0.f, 0.f, 0.f};

    // ---- prologue: W(kt=0) -> Wl[0]; X(q=0) -> Xl[0] ----
#pragma unroll
    for (int t = 0; t < 4; ++t) gload16(&Wl[0][(t * 512 + tid) * 8], gw[t]);
#pragma unroll
    for (int j = 0; j < 6; ++j) {
        int s = wid + j * 8;
        if (s < XSEG) gload16(&Xl[0][(s * 64 + lane) * 8], xpn + xsoff[j]);
    }
    asm volatile("s_waitcnt vmcnt(0)" ::: "memory");
    __builtin_amdgcn_s_barrier();
    __builtin_amdgcn_sched_barrier(0);

    int wpar = 0;
    for (int q = 0; q < 4; ++q) {
        const unsigned short* Xb = Xl[q & 1];
        unsigned short* Xn = Xl[(q & 1) ^ 1];
        const bool qlast = (q == 3);
#pragma unroll
        for (int tap = 0; tap < 9; ++tap) {
            const unsigned short* Wb = Wl[wpar];
            unsigned short* Wn = Wl[wpar ^ 1];
            const int kh = tap / 3, kw = tap % 3;               // compile-time
            const int tapshift = (kh * 58 + kw) * 64;           // shorts
            const bool lastkt = qlast && (tap == 8);

            // issue W(kt+1) first (older than X seg -> vmcnt(1) drains W fully)
            if (!lastkt) {
                const int tap1 = (tap == 8) ? 0 : tap + 1;
                const int woff = tap1 * 256 + ((tap == 8) ? (q + 1) : q) * 64;
#pragma unroll
                for (int t = 0; t < 4; ++t)
                    gload16(&Wn[(t * 512 + tid) * 8], gw[t] + woff);
            }
            __builtin_amdgcn_sched_barrier(0);
            // issue one X(q+1) segment (taps 0..5 only; >=3-kt cover before use)
            if (tap < 6) {
                if (!qlast) {
                    int s = wid + tap * 8;
                    if (s < XSEG)
                        gload16(&Xn[(s * 64 + lane) * 8], xpn + xsoff[tap] + (q + 1) * 64);
                }
            }

            // ---- compute: 2 k-halves of 32, 28 MFMA each ----
#pragma unroll
            for (int ks = 0; ks < 2; ++ks) {
                short8 a[4], b[7];
                const int k4 = kq + ks * 4;
#pragma unroll
                for (int af = 0; af < 4; ++af)
                    a[af] = *(const short8*)&Wb[baseA + af * 1024 + ((k4 ^ swA) * 8)];
#pragma unroll
                for (int xf = 0; xf < 7; ++xf) {
                    int c = k4 ^ ((owl[xf] + kw) & 7);
                    b[xf] = *(const short8*)&Xb[rcb[xf] + tapshift + c * 8];
                }
                __builtin_amdgcn_s_setprio(1);
#pragma unroll
                for (int af = 0; af < 4; ++af)
#pragma unroll
                    for (int xf = 0; xf < 7; ++xf)
                        acc[af][xf] = __builtin_amdgcn_mfma_f32_16x16x32_bf16(
                            a[af], b[xf], acc[af][xf], 0, 0, 0);
                __builtin_amdgcn_s_setprio(0);
            }

            // ---- counted drain + single barrier per kt ----
            if (!lastkt) {
                if (!qlast && tap < 6) {
                    asm volatile("s_waitcnt vmcnt(1)" ::: "memory");  // X seg stays in flight
                } else {
                    asm volatile("s_waitcnt vmcnt(0)" ::: "memory");
                }
                __builtin_amdgcn_s_barrier();
                __builtin_amdgcn_sched_barrier(0);
            }
            wpar ^= 1;
        }
    }

    // ---- epilogue: col = lane&15 -> pixel, row = (lane>>4)*4+reg -> oc ----
    float* outn = out + (size_t)n * (OUT_C * HH * WW) + pix0;
#pragma unroll
    for (int xf = 0; xf < 7; ++xf) {
        int pl = wn * 112 + xf * 16 + rlo;
        float* op = outn + pl;
#pragma unroll
        for (int af = 0; af < 4; ++af) {
            int oc = wm * 64 + af * 16 + kq * 4;
#pragma unroll
            for (int r = 0; r < 4; ++r)
                op[(size_t)(oc + r) * (HH * WW)] = acc[af][xf][r];
        }
    }
}

extern "C" void kernel_launch(void* const* d_in, const int* in_sizes, int n_in,
                              void* d_out, int out_size, void* d_ws, size_t ws_size,
                              hipStream_t stream) {
    const float* x = (const float*)d_in[0];
    const float* wgt = (const float*)d_in[1];
    float* out = (float*)d_out;

    unsigned short* xpad = (unsigned short*)d_ws;                       // 55.1 MB
    size_t xpad_bytes = (size_t)NB * HP * WP * IN_C * 2;
    unsigned short* wtx = (unsigned short*)((char*)d_ws + xpad_bytes);  // 1.18 MB

    hipLaunchKernelGGL(pad_nhwc, dim3(NB * HP), dim3(256), 0, stream, x, xpad);
    hipLaunchKernelGGL(wconv, dim3((OUT_C * 2304) / 256), dim3(256), 0, stream, wgt, wtx);
    hipLaunchKernelGGL(conv_mfma, dim3(NTILE), dim3(512), 0, stream, xpad, wtx, out);
}

// Round 5
// 183.129 us; speedup vs baseline: 1.1095x; 1.1095x over previous
//
#include <hip/hip_runtime.h>
#include <hip/hip_bf16.h>
#include <stdint.h>

#define IN_C 256
#define OUT_C 256
#define HH 56
#define WW 56
#define NB 32
#define HP 58
#define WP 58

#define BMP 112          // pixels per block = 2 output rows
#define NTILE 896        // 32 images * 28 row-pairs = 8*112 (XCD-bijective)
#define XCHUNKS 1856     // 4 rows * 58 cols * 8 ic-chunks
#define XSHORTS 14848    // 29696 B

typedef __attribute__((ext_vector_type(8))) short short8;
typedef __attribute__((ext_vector_type(4))) float float4_t;

typedef const __attribute__((address_space(1))) unsigned int guint_t;
typedef __attribute__((address_space(3))) unsigned int luint_t;

__device__ __forceinline__ unsigned short f2bf(float f) {
    union { float f; unsigned u; } v; v.f = f;
    unsigned r = v.u + 0x7FFF + ((v.u >> 16) & 1);   // RNE
    return (unsigned short)(r >> 16);
}

__device__ __forceinline__ void gload16(void* lds, const void* g) {
    __builtin_amdgcn_global_load_lds((guint_t*)g, (luint_t*)lds, 16, 0, 0);
}

// ---------------- pre-pass 1: NCHW f32 -> padded NHWC bf16 ----------------
__global__ __launch_bounds__(256) void pad_nhwc(const float* __restrict__ x,
                                                unsigned short* __restrict__ xpad) {
    __shared__ float lds[WW * 257];
    int bid = blockIdx.x;
    int n = bid / HP, h = bid % HP;
    unsigned short* dstRow = xpad + (size_t)(n * HP + h) * WP * IN_C;
    bool hin = (h >= 1 && h <= HH);
    if (hin) {
        const float* src = x + (size_t)n * IN_C * (HH * WW) + (h - 1) * WW;
        for (int e = threadIdx.x; e < IN_C * WW; e += 256) {
            int ic = e / WW, w = e - ic * WW;
            lds[w * 257 + ic] = src[(size_t)ic * (HH * WW) + w];
        }
    }
    __syncthreads();
    for (int e = threadIdx.x; e < WP * (IN_C / 8); e += 256) {
        int wo = e / (IN_C / 8);
        int icc = e - wo * (IN_C / 8);
        short8 v = {0, 0, 0, 0, 0, 0, 0, 0};
        if (hin && wo >= 1 && wo <= WW) {
            const float* p = &lds[(wo - 1) * 257 + icc * 8];
#pragma unroll
            for (int j = 0; j < 8; ++j) v[j] = (short)f2bf(p[j]);
        }
        *(short8*)(dstRow + wo * IN_C + icc * 8) = v;
    }
}

// ---------- pre-pass 2: OIHW f32 -> A-fragment-ready wfr[q][tap][wm][ks][af][lane][8] ----------
// element: oc = wm*64+af*16+(lane&15), ic = q*64 + ks*32 + (lane>>4)*8 + j, at tap
__global__ __launch_bounds__(256) void wconv(const float* __restrict__ w,
                                             unsigned short* __restrict__ wfr) {
    int i = blockIdx.x * 256 + threadIdx.x;      // chunk index, 73728 total
    int lane = i & 63;
    int af = (i >> 6) & 3;
    int ks = (i >> 8) & 1;
    int wm = (i >> 9) & 3;
    int qt = i >> 11;          // 0..35
    int tap = qt % 9;
    int q = qt / 9;
    int oc = wm * 64 + af * 16 + (lane & 15);
    int icb = q * 64 + ks * 32 + (lane >> 4) * 8;
    unsigned short* dst = wfr + (size_t)i * 8;
#pragma unroll
    for (int j = 0; j < 8; ++j)
        dst[j] = f2bf(w[((size_t)oc * 256 + icb + j) * 9 + tap]);
}

// ---------------- main: 4-wave blocks, X-slab in LDS, W direct from L2 ----------------
__global__ __launch_bounds__(256, 3) void conv_mfma(const unsigned short* __restrict__ xpad,
                                                    const unsigned short* __restrict__ wfr,
                                                    float* __restrict__ out) {
    __shared__ unsigned short Xl[XSHORTS];   // 4 rows x 58 cols x 64 ic (29 KB), swizzled

    const int tid = threadIdx.x;
    const int lane = tid & 63;
    const int wm = tid >> 6;                 // 0..3 : 64-oc slice

    const int bid = blockIdx.x;
    const int tile = (bid & 7) * 112 + (bid >> 3);   // bijective XCD swizzle (896 = 8*112)
    const int n = tile / 28;
    const int rg = tile - n * 28;
    const int oh0 = rg * 2;                  // padded rows oh0 .. oh0+3
    const int pix0 = rg * BMP;

    const unsigned short* xpn = xpad + (size_t)n * HP * WP * IN_C;

    // ---- b-frag persistent addressing ----
    const int rlo = lane & 15;
    const int kq = lane >> 4;
    const int t7b = rlo & 7;
    int rcb[7];                              // byte offset of (ohr,ow) cell
#pragma unroll
    for (int xf = 0; xf < 7; ++xf) {
        int pl = xf * 16 + rlo;              // 0..111
        int ohr = (pl >= 56) ? 1 : 0;
        int ow = pl - 56 * ohr;
        rcb[xf] = (ohr * 58 + ow) * 128;
    }

    const unsigned short* wsl = wfr + (size_t)wm * 4096;   // this wave's oc-slice

    float4_t acc[4][7];
#pragma unroll
    for (int af = 0; af < 4; ++af)
#pragma unroll
        for (int xf = 0; xf < 7; ++xf) acc[af][xf] = {0.f, 0.f, 0.f, 0.f};

    for (int q = 0; q < 4; ++q) {
        // wait all waves done reading previous slab, then restage
        if (q) {
            asm volatile("s_waitcnt lgkmcnt(0)" ::: "memory");
            __builtin_amdgcn_s_barrier();
        }
#pragma unroll
        for (int k = 0; k < 8; ++k) {
            int ci = tid + k * 256;
            if (ci < XCHUNKS) {
                int rc = ci >> 3, pc = ci & 7;
                int row = rc / 58, col = rc - row * 58;
                gload16(&Xl[ci * 8],
                        xpn + ((size_t)(oh0 + row) * WP + col) * IN_C + q * 64 +
                            (pc ^ (col & 7)) * 8);
            }
        }
        asm volatile("s_waitcnt vmcnt(0)" ::: "memory");
        __builtin_amdgcn_s_barrier();
        __builtin_amdgcn_sched_barrier(0);

#pragma unroll
        for (int tap = 0; tap < 9; ++tap) {
            const int kh = tap / 3, kw = tap % 3;
            const int tapoff = (kh * 58 + kw) * 128;           // byte, compile-time
            const int t7 = (t7b + kw) & 7;
            const unsigned short* wtap = wsl + (size_t)(q * 9 + tap) * 16384;

#pragma unroll
            for (int ks = 0; ks < 2; ++ks) {
                short8 a[4];
#pragma unroll
                for (int af = 0; af < 4; ++af)
                    a[af] = *(const short8*)(wtap + ((ks * 4 + af) * 64 + lane) * 8);
                const int cph = ((kq + ks * 4) ^ t7) * 16;     // byte
                short8 b[7];
#pragma unroll
                for (int xf = 0; xf < 7; ++xf)
                    b[xf] = *(const short8*)((const char*)Xl + rcb[xf] + tapoff + cph);
                __builtin_amdgcn_s_setprio(1);
#pragma unroll
                for (int xf = 0; xf < 7; ++xf)
#pragma unroll
                    for (int af = 0; af < 4; ++af)
                        acc[af][xf] = __builtin_amdgcn_mfma_f32_16x16x32_bf16(
                            a[af], b[xf], acc[af][xf], 0, 0, 0);
                __builtin_amdgcn_s_setprio(0);
            }
        }
    }

    // ---- epilogue: C col = lane&15 -> pixel, row = kq*4+reg -> oc ----
    float* outn = out + (size_t)n * (OUT_C * HH * WW) + pix0;
#pragma unroll
    for (int xf = 0; xf < 7; ++xf) {
        float* op = outn + xf * 16 + rlo;
#pragma unroll
        for (int af = 0; af < 4; ++af) {
            int oc = wm * 64 + af * 16 + kq * 4;
#pragma unroll
            for (int r = 0; r < 4; ++r)
                op[(size_t)(oc + r) * (HH * WW)] = acc[af][xf][r];
        }
    }
}

extern "C" void kernel_launch(void* const* d_in, const int* in_sizes, int n_in,
                              void* d_out, int out_size, void* d_ws, size_t ws_size,
                              hipStream_t stream) {
    const float* x = (const float*)d_in[0];
    const float* wgt = (const float*)d_in[1];
    float* out = (float*)d_out;

    unsigned short* xpad = (unsigned short*)d_ws;                       // 55.1 MB
    size_t xpad_bytes = (size_t)NB * HP * WP * IN_C * 2;
    unsigned short* wfr = (unsigned short*)((char*)d_ws + xpad_bytes);  // 1.18 MB

    hipLaunchKernelGGL(pad_nhwc, dim3(NB * HP), dim3(256), 0, stream, x, xpad);
    hipLaunchKernelGGL(wconv, dim3(288), dim3(256), 0, stream, wgt, wfr);
    hipLaunchKernelGGL(conv_mfma, dim3(NTILE), dim3(256), 0, stream, xpad, wfr, out);
}

// Round 6
// 157.707 us; speedup vs baseline: 1.2883x; 1.1612x over previous
//
#include <hip/hip_runtime.h>
#include <hip/hip_bf16.h>
#include <stdint.h>

#define IN_C 256
#define OUT_C 256
#define HH 56
#define WW 56
#define NB 32
#define HP 58
#define WP 58

#define BMP 112          // pixels per block = 2 output rows
#define NTILE 896        // 32 images * 28 row-pairs = 8*112 (XCD-bijective)
#define XCHUNKS 1856     // 4 rows * 58 cols * 8 ic-chunks
#define XSHORTS 14848    // 29696 B per slab

typedef __attribute__((ext_vector_type(8))) short short8;
typedef __attribute__((ext_vector_type(4))) float float4_t;

typedef const __attribute__((address_space(1))) unsigned int guint_t;
typedef __attribute__((address_space(3))) unsigned int luint_t;

__device__ __forceinline__ unsigned short f2bf(float f) {
    union { float f; unsigned u; } v; v.f = f;
    unsigned r = v.u + 0x7FFF + ((v.u >> 16) & 1);   // RNE
    return (unsigned short)(r >> 16);
}

__device__ __forceinline__ void gload16(void* lds, const void* g) {
    __builtin_amdgcn_global_load_lds((guint_t*)g, (luint_t*)lds, 16, 0, 0);
}

// ---------------- pre-pass 1: NCHW f32 -> padded NHWC bf16 ----------------
__global__ __launch_bounds__(256) void pad_nhwc(const float* __restrict__ x,
                                                unsigned short* __restrict__ xpad) {
    __shared__ float lds[WW * 257];
    int bid = blockIdx.x;
    int n = bid / HP, h = bid % HP;
    unsigned short* dstRow = xpad + (size_t)(n * HP + h) * WP * IN_C;
    bool hin = (h >= 1 && h <= HH);
    if (hin) {
        const float* src = x + (size_t)n * IN_C * (HH * WW) + (h - 1) * WW;
        for (int e = threadIdx.x; e < IN_C * WW; e += 256) {
            int ic = e / WW, w = e - ic * WW;
            lds[w * 257 + ic] = src[(size_t)ic * (HH * WW) + w];
        }
    }
    __syncthreads();
    for (int e = threadIdx.x; e < WP * (IN_C / 8); e += 256) {
        int wo = e / (IN_C / 8);
        int icc = e - wo * (IN_C / 8);
        short8 v = {0, 0, 0, 0, 0, 0, 0, 0};
        if (hin && wo >= 1 && wo <= WW) {
            const float* p = &lds[(wo - 1) * 257 + icc * 8];
#pragma unroll
            for (int j = 0; j < 8; ++j) v[j] = (short)f2bf(p[j]);
        }
        *(short8*)(dstRow + wo * IN_C + icc * 8) = v;
    }
}

// ---------- pre-pass 2: OIHW f32 -> A-fragment-ready wfr[q][tap][wm][ks][af][lane][8] ----------
__global__ __launch_bounds__(256) void wconv(const float* __restrict__ w,
                                             unsigned short* __restrict__ wfr) {
    int i = blockIdx.x * 256 + threadIdx.x;      // chunk index, 73728 total
    int lane = i & 63;
    int af = (i >> 6) & 3;
    int ks = (i >> 8) & 1;
    int wm = (i >> 9) & 3;
    int qt = i >> 11;          // 0..35
    int tap = qt % 9;
    int q = qt / 9;
    int oc = wm * 64 + af * 16 + (lane & 15);
    int icb = q * 64 + ks * 32 + (lane >> 4) * 8;
    unsigned short* dst = wfr + (size_t)i * 8;
#pragma unroll
    for (int j = 0; j < 8; ++j)
        dst[j] = f2bf(w[((size_t)oc * 256 + icb + j) * 9 + tap]);
}

// ---------------- main: 4-wave blocks, reg-pipelined frags, dbuf X slab ----------------
__global__ __launch_bounds__(256, 2) void conv_mfma(const unsigned short* __restrict__ xpad,
                                                    const unsigned short* __restrict__ wfr,
                                                    float* __restrict__ out) {
    __shared__ unsigned short Xl[2][XSHORTS];   // 2 x (4 rows x 58 cols x 64 ic), swizzled

    const int tid = threadIdx.x;
    const int lane = tid & 63;
    const int wm = tid >> 6;                 // 0..3 : 64-oc slice

    const int bid = blockIdx.x;
    const int tile = (bid & 7) * 112 + (bid >> 3);   // bijective XCD swizzle (896 = 8*112)
    const int n = tile / 28;
    const int rg = tile - n * 28;
    const int oh0 = rg * 2;                  // padded rows oh0 .. oh0+3
    const int pix0 = rg * BMP;

    const unsigned short* xpn = xpad + (size_t)n * HP * WP * IN_C;

    // ---- per-thread X-staging chunk addressing (8 chunks) ----
    int xgo[8];                              // global short-offset (q term added at issue)
#pragma unroll
    for (int k = 0; k < 8; ++k) {
        int ci = tid + k * 256;
        int cc = (ci < XCHUNKS) ? ci : (XCHUNKS - 1);
        int rc = cc >> 3, pc = cc & 7;
        int row = rc / 58, col = rc - row * 58;
        xgo[k] = ((oh0 + row) * WP + col) * IN_C + (pc ^ (col & 7)) * 8;
    }

    // ---- b-frag persistent addressing ----
    const int rlo = lane & 15;
    const int kq = lane >> 4;
    const int t7b = rlo & 7;
    int rcb[7];                              // byte offset of (ohr,ow) cell
#pragma unroll
    for (int xf = 0; xf < 7; ++xf) {
        int pl = xf * 16 + rlo;              // 0..111
        int ohr = (pl >= 56) ? 1 : 0;
        int ow = pl - 56 * ohr;
        rcb[xf] = (ohr * 58 + ow) * 128;
    }

    const unsigned short* wsl = wfr + (size_t)wm * 4096;   // this wave's oc-slice

    float4_t acc[4][7];
#pragma unroll
    for (int af = 0; af < 4; ++af)
#pragma unroll
        for (int xf = 0; xf < 7; ++xf) acc[af][xf] = {0.f, 0.f, 0.f, 0.f};

    short8 Af0[4], Bf0[7], Af1[4], Bf1[7];

#define LOAD_STEP(AF, BF, WQ, TAP, KS, SLAB)                                       \
    {                                                                               \
        const unsigned short* wtap_ = wsl + ((size_t)((WQ)*9 + (TAP))) * 16384;     \
        _Pragma("unroll")                                                           \
        for (int af_ = 0; af_ < 4; ++af_)                                           \
            AF[af_] = *(const short8*)(wtap_ + (((KS)*4 + af_) * 64 + lane) * 8);   \
        const int cph_ = ((kq + (KS)*4) ^ ((t7b + ((TAP) % 3)) & 7)) * 16;          \
        const int tapoff_ = (((TAP) / 3) * 58 + ((TAP) % 3)) * 128;                 \
        _Pragma("unroll")                                                           \
        for (int xf_ = 0; xf_ < 7; ++xf_)                                           \
            BF[xf_] = *(const short8*)((const char*)(SLAB) + rcb[xf_] + tapoff_ + cph_); \
    }

#define MMA_STEP(AF, BF)                                                            \
    {                                                                               \
        __builtin_amdgcn_s_setprio(1);                                              \
        _Pragma("unroll")                                                           \
        for (int xf_ = 0; xf_ < 7; ++xf_)                                           \
            _Pragma("unroll")                                                       \
            for (int af_ = 0; af_ < 4; ++af_)                                       \
                acc[af_][xf_] = __builtin_amdgcn_mfma_f32_16x16x32_bf16(            \
                    AF[af_], BF[xf_], acc[af_][xf_], 0, 0, 0);                      \
        __builtin_amdgcn_s_setprio(0);                                              \
    }

    // ---- prologue: stage X slab q=0 into Xl[0] ----
#pragma unroll
    for (int k = 0; k < 7; ++k)
        gload16(&Xl[0][(tid + k * 256) * 8], xpn + xgo[k]);
    if (tid < XCHUNKS - 7 * 256)
        gload16(&Xl[0][(tid + 7 * 256) * 8], xpn + xgo[7]);
    asm volatile("s_waitcnt vmcnt(0)" ::: "memory");
    __builtin_amdgcn_s_barrier();
    LOAD_STEP(Af0, Bf0, 0, 0, 0, Xl[0]);

    for (int q = 0; q < 4; ++q) {
        const unsigned short* slab = Xl[q & 1];
        unsigned short* nslab = Xl[(q & 1) ^ 1];
        const bool qn = (q < 3);
#pragma unroll
        for (int s = 0; s < 18; ++s) {
            const int s1 = s + 1;
            // prefetch next step's fragments into the other buffer
            if (s1 < 18) {
                if (s & 1) {
                    LOAD_STEP(Af0, Bf0, q, s1 / 2, s1 & 1, slab);
                } else {
                    LOAD_STEP(Af1, Bf1, q, s1 / 2, s1 & 1, slab);
                }
            }
            // drip-stage next q's X slab: 2 chunks at s = 4,6,8,10
            if (qn && s >= 4 && s <= 10 && (s & 1) == 0) {
                const int j0 = s - 4;                 // 0,2,4,6
                gload16(&nslab[(tid + j0 * 256) * 8], xpn + xgo[j0] + (q + 1) * 64);
                if (j0 + 1 < 7) {
                    gload16(&nslab[(tid + (j0 + 1) * 256) * 8],
                            xpn + xgo[j0 + 1] + (q + 1) * 64);
                } else {
                    if (tid < XCHUNKS - 7 * 256)
                        gload16(&nslab[(tid + 7 * 256) * 8], xpn + xgo[7] + (q + 1) * 64);
                }
            }
            __builtin_amdgcn_sched_barrier(0);        // keep loads issued before MFMA cluster
            if (s & 1) {
                MMA_STEP(Af1, Bf1);
            } else {
                MMA_STEP(Af0, Bf0);
            }
        }
        if (qn) {
            asm volatile("s_waitcnt vmcnt(0)" ::: "memory");   // all old loads done (cheap)
            __builtin_amdgcn_s_barrier();
            // first step of next q (parity 0)
            if ((q & 1) == 0) {
                LOAD_STEP(Af0, Bf0, q + 1, 0, 0, Xl[1]);
            } else {
                LOAD_STEP(Af0, Bf0, q + 1, 0, 0, Xl[0]);
            }
        }
    }

    // ---- epilogue: C col = lane&15 -> pixel, row = kq*4+reg -> oc ----
    float* outn = out + (size_t)n * (OUT_C * HH * WW) + pix0;
#pragma unroll
    for (int xf = 0; xf < 7; ++xf) {
        float* op = outn + xf * 16 + rlo;
#pragma unroll
        for (int af = 0; af < 4; ++af) {
            int oc = wm * 64 + af * 16 + kq * 4;
#pragma unroll
            for (int r = 0; r < 4; ++r)
                op[(size_t)(oc + r) * (HH * WW)] = acc[af][xf][r];
        }
    }
}

extern "C" void kernel_launch(void* const* d_in, const int* in_sizes, int n_in,
                              void* d_out, int out_size, void* d_ws, size_t ws_size,
                              hipStream_t stream) {
    const float* x = (const float*)d_in[0];
    const float* wgt = (const float*)d_in[1];
    float* out = (float*)d_out;

    unsigned short* xpad = (unsigned short*)d_ws;                       // 55.1 MB
    size_t xpad_bytes = (size_t)NB * HP * WP * IN_C * 2;
    unsigned short* wfr = (unsigned short*)((char*)d_ws + xpad_bytes);  // 1.18 MB

    hipLaunchKernelGGL(pad_nhwc, dim3(NB * HP), dim3(256), 0, stream, x, xpad);
    hipLaunchKernelGGL(wconv, dim3(288), dim3(256), 0, stream, wgt, wfr);
    hipLaunchKernelGGL(conv_mfma, dim3(NTILE), dim3(256), 0, stream, xpad, wfr, out);
}